// Round 1
// baseline (218.553 us; speedup 1.0000x reference)
//
#include <hip/hip_runtime.h>
#include <hip/hip_bf16.h>

typedef __attribute__((ext_vector_type(8))) short short8;
typedef __attribute__((ext_vector_type(4))) float floatx4;
typedef __attribute__((ext_vector_type(4))) unsigned short ushortx4;

#define N_ROWS 32768
#define D_DIM  128
#define H_KEYS 8192
#define C_COLS 100
#define BM     64
#define BH     128
#define P_STRIDE  136   // ushorts per P row (128 + 8 pad -> 2-way-max LDS banks)
#define OL_STRIDE 113   // floats per OL row (odd -> conflict-free epilogue)

__device__ __forceinline__ unsigned short f2bf(float f) {
  union { float f; unsigned int u; } v; v.f = f;
  unsigned int r = v.u + 0x7fffu + ((v.u >> 16) & 1u);  // RNE
  return (unsigned short)(r >> 16);
}

// Pack a row-major [R x 128] fp32 matrix into MFMA A/B fragment order:
// dst[(rowtile*4 + chunk)*64 + lane][j] = src[16*rowtile + (lane&15)][32*chunk + (lane>>4)*8 + j]
// One thread per (rowtile, chunk, lane) -> one 16B store.
__global__ void pack_frag_kernel(const float* __restrict__ src,
                                 const float* __restrict__ temp,
                                 int use_temp_scale,
                                 unsigned short* __restrict__ dst) {
  int gid = blockIdx.x * 256 + threadIdx.x;
  int lane = gid & 63;
  int c = (gid >> 6) & 3;
  int rt = gid >> 8;
  float scale = use_temp_scale ? (2.0f / temp[0]) : 1.0f;
  int row = rt * 16 + (lane & 15);
  int d0 = c * 32 + (lane >> 4) * 8;
  const float* s = src + row * D_DIM + d0;
  short8 o;
#pragma unroll
  for (int j = 0; j < 8; ++j) o[j] = (short)f2bf(s[j] * scale);
  *(short8*)(dst + (size_t)gid * 8) = o;
}

// k_sq[h] = sum_d keys[h][d]^2 / temp   (one wave per key, coalesced float2)
__global__ void ksq_kernel(const float* __restrict__ keys,
                           const float* __restrict__ temp,
                           float* __restrict__ ksq) {
  int wid = (blockIdx.x * 256 + threadIdx.x) >> 6;  // key index
  int lane = threadIdx.x & 63;
  const float2* row = (const float2*)(keys + (size_t)wid * D_DIM);
  float2 v = row[lane];
  float s = v.x * v.x + v.y * v.y;
#pragma unroll
  for (int off = 32; off > 0; off >>= 1) s += __shfl_down(s, off);
  if (lane == 0) ksq[wid] = s / temp[0];
}

// Pack values [H x 100] into PV B-fragment order, padded to 112 cols with a
// ones-column at col 100 (so O[:,100] = sum_h P = softmax denominator).
// vp[((g*7 + ct)*64 + lane)][j] = Vpad[32g + (lane>>4)*8 + j][16ct + (lane&15)]
__global__ void pack_v_kernel(const float* __restrict__ values,
                              unsigned short* __restrict__ vp) {
  __shared__ float vt[32 * 113];
  int g = blockIdx.x;
  int tid = threadIdx.x;
  for (int idx = tid; idx < 32 * 112; idx += 256) {
    int k = idx / 112, col = idx - k * 112;
    float val;
    if (col < C_COLS) val = values[(size_t)(g * 32 + k) * C_COLS + col];
    else val = (col == C_COLS) ? 1.0f : 0.0f;
    vt[k * 113 + col] = val;
  }
  __syncthreads();
  for (int u = tid; u < 7 * 64; u += 256) {
    int ct = u >> 6, l = u & 63;
    int n0 = l & 15, q = l >> 4;
    short8 o;
#pragma unroll
    for (int j = 0; j < 8; ++j) o[j] = (short)f2bf(vt[(q * 8 + j) * 113 + ct * 16 + n0]);
    *(short8*)(vp + ((size_t)(g * 7 + ct) * 64 + l) * 8) = o;
  }
}

// Fused RBF attention: per 64-row block, stream all 8192 keys in 128-key tiles.
// S^T = K.X^T via MFMA (acc reg index runs along keys -> contiguous P writes),
// P = exp(S - ksq) in bf16 -> LDS, O += P.V via MFMA. No online max needed:
// logits bounded (|2xk/T| <= ~11). Epilogue divides by the ones-column sum.
__global__ __launch_bounds__(256, 2)
void attn_rbf_kernel(const unsigned short* __restrict__ xp,
                     const unsigned short* __restrict__ kp,
                     const float* __restrict__ ksq,
                     const unsigned short* __restrict__ vp,
                     float* __restrict__ out) {
  __shared__ __align__(16) char smem[BM * OL_STRIDE * 4];  // 28928 B; P tile aliases front 17408 B
  unsigned short* P = (unsigned short*)smem;
  float* OL = (float*)smem;

  const int tid = threadIdx.x;
  const int w = tid >> 6;       // wave 0..3
  const int lane = tid & 63;
  const int n0 = lane & 15;
  const int q = lane >> 4;
  const int b = blockIdx.x;     // row block: rows [64b, 64b+64)

  // x fragments for all 64 rows (B-operand of S^T): 64 VGPRs, resident all kernel
  short8 xf[4][4];
#pragma unroll
  for (int rt = 0; rt < 4; ++rt)
#pragma unroll
    for (int c = 0; c < 4; ++c)
      xf[rt][c] = *(const short8*)(xp + ((size_t)((b * 4 + rt) * 4 + c) * 64 + lane) * 8);

  floatx4 oacc[4][2];
#pragma unroll
  for (int rt = 0; rt < 4; ++rt)
#pragma unroll
    for (int u = 0; u < 2; ++u)
      oacc[rt][u] = (floatx4){0.f, 0.f, 0.f, 0.f};

  const int nct = (w < 3) ? 2 : 1;  // waves own C-tiles {0,1},{2,3},{4,5},{6}
  const int ct0 = w * 2;

  for (int it = 0; it < H_KEYS / BH; ++it) {
    // ---- global prefetch (all register-direct, L2-resident streams) ----
    short8 kf[2][4];
#pragma unroll
    for (int kt = 0; kt < 2; ++kt)
#pragma unroll
      for (int c = 0; c < 4; ++c)
        kf[kt][c] = *(const short8*)(kp + ((size_t)((it * 8 + w * 2 + kt) * 4 + c) * 64 + lane) * 8);

    floatx4 ksq4[2];
#pragma unroll
    for (int kt = 0; kt < 2; ++kt)
      ksq4[kt] = *(const floatx4*)(ksq + it * BH + w * 32 + kt * 16 + q * 4);

    short8 vf[4][2];
#pragma unroll
    for (int c = 0; c < 4; ++c)
#pragma unroll
      for (int u = 0; u < 2; ++u)
        if (u < nct)
          vf[c][u] = *(const short8*)(vp + ((size_t)((it * 4 + c) * 7 + (ct0 + u)) * 64 + lane) * 8);

    // ---- S^T = K . X^T (wave w owns keys [32w, 32w+32) of this tile) ----
#pragma unroll
    for (int kt = 0; kt < 2; ++kt) {
      floatx4 s[4];
#pragma unroll
      for (int rt = 0; rt < 4; ++rt) s[rt] = (floatx4){0.f, 0.f, 0.f, 0.f};
#pragma unroll
      for (int c = 0; c < 4; ++c)
#pragma unroll
        for (int rt = 0; rt < 4; ++rt)
          s[rt] = __builtin_amdgcn_mfma_f32_16x16x32_bf16(kf[kt][c], xf[rt][c], s[rt], 0, 0, 0);
      // exp + pack 4 consecutive keys -> one ds_write_b64
#pragma unroll
      for (int rt = 0; rt < 4; ++rt) {
        ushortx4 pk;
#pragma unroll
        for (int i = 0; i < 4; ++i)
          pk[i] = f2bf(__expf(s[rt][i] - ksq4[kt][i]));
        *(ushortx4*)(P + (rt * 16 + n0) * P_STRIDE + w * 32 + kt * 16 + q * 4) = pk;
      }
    }
    __syncthreads();

    // ---- O += P . V (wave w owns its C-tiles, all 64 rows) ----
#pragma unroll
    for (int c = 0; c < 4; ++c) {
      short8 pf[4];
#pragma unroll
      for (int rt = 0; rt < 4; ++rt)
        pf[rt] = *(const short8*)(P + (rt * 16 + n0) * P_STRIDE + c * 32 + q * 8);
#pragma unroll
      for (int u = 0; u < 2; ++u)
        if (u < nct)
#pragma unroll
          for (int rt = 0; rt < 4; ++rt)
            oacc[rt][u] = __builtin_amdgcn_mfma_f32_16x16x32_bf16(pf[rt], vf[c][u], oacc[rt][u], 0, 0, 0);
    }
    __syncthreads();
  }

  // ---- epilogue: O tiles -> LDS fp32, divide by denominator col, coalesced store ----
#pragma unroll
  for (int rt = 0; rt < 4; ++rt)
#pragma unroll
    for (int u = 0; u < 2; ++u)
      if (u < nct)
#pragma unroll
        for (int i = 0; i < 4; ++i)
          OL[(rt * 16 + q * 4 + i) * OL_STRIDE + (ct0 + u) * 16 + n0] = oacc[rt][u][i];
  __syncthreads();

  float* outb = out + (size_t)b * (BM * C_COLS);
  for (int idx = tid; idx < BM * C_COLS; idx += 256) {
    int n = idx / C_COLS;
    int cc = idx - n * C_COLS;
    outb[idx] = OL[n * OL_STRIDE + cc] / OL[n * OL_STRIDE + 100];
  }
}

extern "C" void kernel_launch(void* const* d_in, const int* in_sizes, int n_in,
                              void* d_out, int out_size, void* d_ws, size_t ws_size,
                              hipStream_t stream) {
  (void)in_sizes; (void)n_in; (void)out_size; (void)ws_size;
  const float* x      = (const float*)d_in[0];
  const float* keys   = (const float*)d_in[1];
  const float* values = (const float*)d_in[2];
  const float* temp   = (const float*)d_in[3];
  float* out = (float*)d_out;

  char* ws = (char*)d_ws;
  unsigned short* xp  = (unsigned short*)(ws);             // 32768*128*2 = 8388608 B
  unsigned short* kp  = (unsigned short*)(ws + 8388608);   // 8192*128*2  = 2097152 B
  unsigned short* vp  = (unsigned short*)(ws + 10485760);  // 8192*112*2  = 1835008 B
  float*          ksq = (float*)(ws + 12320768);           // 8192*4      = 32768 B

  hipLaunchKernelGGL(pack_frag_kernel, dim3(2048), dim3(256), 0, stream, x, temp, 1, xp);
  hipLaunchKernelGGL(pack_frag_kernel, dim3(512),  dim3(256), 0, stream, keys, temp, 0, kp);
  hipLaunchKernelGGL(ksq_kernel,       dim3(2048), dim3(256), 0, stream, keys, temp, ksq);
  hipLaunchKernelGGL(pack_v_kernel,    dim3(256),  dim3(256), 0, stream, values, vp);
  hipLaunchKernelGGL(attn_rbf_kernel,  dim3(512),  dim3(256), 0, stream, xp, kp, ksq, vp, out);
}

// Round 3
// 204.214 us; speedup vs baseline: 1.0702x; 1.0702x over previous
//
#include <hip/hip_runtime.h>
#include <hip/hip_bf16.h>

typedef __attribute__((ext_vector_type(8))) short short8;
typedef __attribute__((ext_vector_type(4))) float floatx4;

#define N_ROWS 32768
#define D_DIM  128
#define H_KEYS 8192
#define C_COLS 100
#define BM     64
#define BH     128
#define P_STRIDE  136   // ushorts per P row (272 B, 16B-aligned rows)
#define P_BYTES   (BM * P_STRIDE * 2)   // 17408 B per buffer
#define OL_STRIDE 113   // floats per OL row (odd -> conflict-free epilogue)
#define LOG2E 1.4426950408889634f

__device__ __forceinline__ unsigned short f2bf(float f) {
  union { float f; unsigned int u; } v; v.f = f;
  unsigned int r = v.u + 0x7fffu + ((v.u >> 16) & 1u);  // RNE
  return (unsigned short)(r >> 16);
}

// v_cvt_pk_bf16_f32: two fp32 -> packed bf16 (a in low 16, b in high 16)
__device__ __forceinline__ unsigned int pk2bf(float a, float b) {
  union { __hip_bfloat162 h; unsigned int u; } c;
  c.h = __float22bfloat162_rn(float2{a, b});
  return c.u;
}

// Pack keys [8192 x 128] fp32 into MFMA A-fragment order, scaled by 2*log2e/T:
// dst[(rowtile*4 + chunk)*64 + lane][j] = s*src[16*rowtile + (lane&15)][32*chunk + (lane>>4)*8 + j]
__global__ void pack_k_kernel(const float* __restrict__ src,
                              const float* __restrict__ temp,
                              unsigned short* __restrict__ dst) {
  int gid = blockIdx.x * 256 + threadIdx.x;
  int lane = gid & 63;
  int c = (gid >> 6) & 3;
  int rt = gid >> 8;
  float scale = 2.0f * LOG2E / temp[0];
  int row = rt * 16 + (lane & 15);
  int d0 = c * 32 + (lane >> 4) * 8;
  const float* s = src + row * D_DIM + d0;
  short8 o;
#pragma unroll
  for (int j = 0; j < 8; ++j) o[j] = (short)f2bf(s[j] * scale);
  *(short8*)(dst + (size_t)gid * 8) = o;
}

// ksq[h] = -sum_d keys[h][d]^2 * log2e / temp  (pre-negated: used as MFMA C-init)
__global__ void ksq_kernel(const float* __restrict__ keys,
                           const float* __restrict__ temp,
                           float* __restrict__ ksq) {
  int wid = (blockIdx.x * 256 + threadIdx.x) >> 6;  // key index
  int lane = threadIdx.x & 63;
  const float2* row = (const float2*)(keys + (size_t)wid * D_DIM);
  float2 v = row[lane];
  float s = v.x * v.x + v.y * v.y;
#pragma unroll
  for (int off = 32; off > 0; off >>= 1) s += __shfl_down(s, off);
  if (lane == 0) ksq[wid] = -s * LOG2E / temp[0];
}

// Pack values [H x 100] into PV B-fragment order, padded to 112 cols with a
// ones-column at col 100 (so O[:,100] = softmax denominator).
__global__ void pack_v_kernel(const float* __restrict__ values,
                              unsigned short* __restrict__ vp) {
  __shared__ float vt[32 * 113];
  int g = blockIdx.x;
  int tid = threadIdx.x;
  for (int idx = tid; idx < 32 * 112; idx += 256) {
    int k = idx / 112, col = idx - k * 112;
    float val;
    if (col < C_COLS) val = values[(size_t)(g * 32 + k) * C_COLS + col];
    else val = (col == C_COLS) ? 1.0f : 0.0f;
    vt[k * 113 + col] = val;
  }
  __syncthreads();
  for (int u = tid; u < 7 * 64; u += 256) {
    int ct = u >> 6, l = u & 63;
    int n0 = l & 15, q = l >> 4;
    short8 o;
#pragma unroll
    for (int j = 0; j < 8; ++j) o[j] = (short)f2bf(vt[(q * 8 + j) * 113 + ct * 16 + n0]);
    *(short8*)(vp + ((size_t)(g * 7 + ct) * 64 + l) * 8) = o;
  }
}

// Fused RBF attention. S^T = Kscaled.X^T with C initialized to -ksq*log2e/T,
// P = exp2(S) in bf16 -> LDS (double-buffered, 1 barrier/iter), O += P.V.
__global__ __launch_bounds__(256, 2)
void attn_rbf_kernel(const float* __restrict__ x,
                     const unsigned short* __restrict__ kp,
                     const float* __restrict__ ksq,
                     const unsigned short* __restrict__ vp,
                     float* __restrict__ out) {
  __shared__ __align__(16) char smem[2 * P_BYTES];  // 34816 B; epilogue OL aliases front
  float* OL = (float*)smem;
  float* rden = (float*)(smem + BM * OL_STRIDE * 4);  // 64 floats at +28928

  const int tid = threadIdx.x;
  const int w = tid >> 6;       // wave 0..3
  const int lane = tid & 63;
  const int n0 = lane & 15;
  const int q = lane >> 4;
  const int b = blockIdx.x;     // row block: rows [64b, 64b+64)

  // Load x rows for this block directly (fp32 row-major), convert to B-fragments.
  short8 xf[4][4];
#pragma unroll
  for (int rt = 0; rt < 4; ++rt)
#pragma unroll
    for (int c = 0; c < 4; ++c) {
      const float* s = x + (size_t)(b * 64 + rt * 16 + n0) * D_DIM + c * 32 + q * 8;
      float4 lo = *(const float4*)s;
      float4 hi = *(const float4*)(s + 4);
      union { short8 v; unsigned int u[4]; } cv;
      cv.u[0] = pk2bf(lo.x, lo.y);
      cv.u[1] = pk2bf(lo.z, lo.w);
      cv.u[2] = pk2bf(hi.x, hi.y);
      cv.u[3] = pk2bf(hi.z, hi.w);
      xf[rt][c] = cv.v;
    }

  floatx4 oacc[4][2];
#pragma unroll
  for (int rt = 0; rt < 4; ++rt)
#pragma unroll
    for (int u = 0; u < 2; ++u)
      oacc[rt][u] = (floatx4){0.f, 0.f, 0.f, 0.f};

  const int nct = (w < 3) ? 2 : 1;  // waves own C-tiles {0,1},{2,3},{4,5},{6}
  const int ct0 = w * 2;

  for (int it = 0; it < H_KEYS / BH; ++it) {
    unsigned short* P = (unsigned short*)(smem + (it & 1) * P_BYTES);

    // ---- global prefetch (L2-resident streams) ----
    short8 kf[2][4];
#pragma unroll
    for (int kt = 0; kt < 2; ++kt)
#pragma unroll
      for (int c = 0; c < 4; ++c)
        kf[kt][c] = *(const short8*)(kp + ((size_t)((it * 8 + w * 2 + kt) * 4 + c) * 64 + lane) * 8);

    floatx4 ksq4[2];
#pragma unroll
    for (int kt = 0; kt < 2; ++kt)
      ksq4[kt] = *(const floatx4*)(ksq + it * BH + w * 32 + kt * 16 + q * 4);

    short8 vf[4][2];
#pragma unroll
    for (int c = 0; c < 4; ++c)
#pragma unroll
      for (int u = 0; u < 2; ++u)
        if (u < nct)
          vf[c][u] = *(const short8*)(vp + ((size_t)((it * 4 + c) * 7 + (ct0 + u)) * 64 + lane) * 8);

    // ---- S^T = K . X^T, C initialized to -ksq (folded softmax bias) ----
#pragma unroll
    for (int kt = 0; kt < 2; ++kt) {
      floatx4 s[4];
#pragma unroll
      for (int rt = 0; rt < 4; ++rt) s[rt] = ksq4[kt];
#pragma unroll
      for (int c = 0; c < 4; ++c)
#pragma unroll
        for (int rt = 0; rt < 4; ++rt)
          s[rt] = __builtin_amdgcn_mfma_f32_16x16x32_bf16(kf[kt][c], xf[rt][c], s[rt], 0, 0, 0);
      // exp2 + packed cvt: 4 keys -> one ds_write_b64
#pragma unroll
      for (int rt = 0; rt < 4; ++rt) {
        uint2 pk;
        pk.x = pk2bf(__builtin_amdgcn_exp2f(s[rt][0]), __builtin_amdgcn_exp2f(s[rt][1]));
        pk.y = pk2bf(__builtin_amdgcn_exp2f(s[rt][2]), __builtin_amdgcn_exp2f(s[rt][3]));
        *(uint2*)(P + (rt * 16 + n0) * P_STRIDE + w * 32 + kt * 16 + q * 4) = pk;
      }
    }
    __syncthreads();  // single barrier: P complete; next iter writes the other buffer

    // ---- O += P . V (wave w owns its C-tiles, all 64 rows) ----
#pragma unroll
    for (int c = 0; c < 4; ++c) {
      short8 pf[4];
#pragma unroll
      for (int rt = 0; rt < 4; ++rt)
        pf[rt] = *(const short8*)(P + (rt * 16 + n0) * P_STRIDE + c * 32 + q * 8);
#pragma unroll
      for (int u = 0; u < 2; ++u)
        if (u < nct)
#pragma unroll
          for (int rt = 0; rt < 4; ++rt)
            oacc[rt][u] = __builtin_amdgcn_mfma_f32_16x16x32_bf16(pf[rt], vf[c][u], oacc[rt][u], 0, 0, 0);
    }
  }
  __syncthreads();  // all waves done reading P before OL overlays it

  // ---- epilogue: O tiles -> LDS fp32, per-row reciprocal, coalesced store ----
#pragma unroll
  for (int rt = 0; rt < 4; ++rt)
#pragma unroll
    for (int u = 0; u < 2; ++u)
      if (u < nct)
#pragma unroll
        for (int i = 0; i < 4; ++i)
          OL[(rt * 16 + q * 4 + i) * OL_STRIDE + (ct0 + u) * 16 + n0] = oacc[rt][u][i];
  __syncthreads();
  if (tid < BM) rden[tid] = 1.0f / OL[tid * OL_STRIDE + 100];
  __syncthreads();

  float* outb = out + (size_t)b * (BM * C_COLS);
  for (int idx = tid; idx < BM * C_COLS; idx += 256) {
    int n = idx / C_COLS;
    int cc = idx - n * C_COLS;
    outb[idx] = OL[n * OL_STRIDE + cc] * rden[n];
  }
}

extern "C" void kernel_launch(void* const* d_in, const int* in_sizes, int n_in,
                              void* d_out, int out_size, void* d_ws, size_t ws_size,
                              hipStream_t stream) {
  (void)in_sizes; (void)n_in; (void)out_size; (void)ws_size;
  const float* x      = (const float*)d_in[0];
  const float* keys   = (const float*)d_in[1];
  const float* values = (const float*)d_in[2];
  const float* temp   = (const float*)d_in[3];
  float* out = (float*)d_out;

  char* ws = (char*)d_ws;
  unsigned short* kp  = (unsigned short*)(ws);             // 8192*128*2 = 2097152 B
  unsigned short* vp  = (unsigned short*)(ws + 2097152);   // 8192*112*2 = 1835008 B
  float*          ksq = (float*)(ws + 3932160);            // 8192*4     = 32768 B

  hipLaunchKernelGGL(pack_k_kernel,   dim3(512),  dim3(256), 0, stream, keys, temp, kp);
  hipLaunchKernelGGL(ksq_kernel,      dim3(2048), dim3(256), 0, stream, keys, temp, ksq);
  hipLaunchKernelGGL(pack_v_kernel,   dim3(256),  dim3(256), 0, stream, values, vp);
  hipLaunchKernelGGL(attn_rbf_kernel, dim3(512),  dim3(256), 0, stream, x, kp, ksq, vp, out);
}